// Round 1
// baseline (366.506 us; speedup 1.0000x reference)
//
#include <hip/hip_runtime.h>
#include <hip/hip_bf16.h>
#include <stdint.h>

// ---------- types ----------
typedef short bf16x8 __attribute__((ext_vector_type(8)));
typedef short bf16x4 __attribute__((ext_vector_type(4)));
typedef float f32x4  __attribute__((ext_vector_type(4)));

__device__ __forceinline__ float b2f(short s) {
  union { float f; uint32_t u; } x;
  x.u = ((uint32_t)(uint16_t)s) << 16;
  return x.f;
}
__device__ __forceinline__ short f2b(float f) {
  union { float f; uint32_t u; } x;
  x.f = f;
  uint32_t r = x.u + 0x7fff + ((x.u >> 16) & 1);  // RNE
  return (short)(r >> 16);
}

__device__ __forceinline__ void gload_lds16(const void* g, void* l) {
  __builtin_amdgcn_global_load_lds(
      (const __attribute__((address_space(1))) void*)g,
      (__attribute__((address_space(3))) void*)l, 16, 0, 0);
}

// ---------- prep: f32 -> bf16 conversions + rope tables ----------
__global__ __launch_bounds__(256)
void prep(const float* __restrict__ x, const float* __restrict__ rope,
          const float* __restrict__ wq, const float* __restrict__ wk,
          const float* __restrict__ wv, const float* __restrict__ wo,
          short* __restrict__ Xb, short* __restrict__ Wqkv, short* __restrict__ Wob,
          float* __restrict__ costab, float* __restrict__ sintab)
{
  const int64_t XN4 = 16777216 / 4;   // x float4 count
  const int64_t WN4 = 1048576 / 4;    // one weight matrix float4 count
  const int64_t total = XN4 + 4 * WN4 + 512;
  for (int64_t i = (int64_t)blockIdx.x * blockDim.x + threadIdx.x; i < total;
       i += (int64_t)gridDim.x * blockDim.x) {
    if (i < XN4) {
      f32x4 v = ((const f32x4*)x)[i];
      bf16x4 o;
#pragma unroll
      for (int j = 0; j < 4; ++j) o[j] = f2b(v[j]);
      ((bf16x4*)Xb)[i] = o;
    } else if (i < XN4 + 3 * WN4) {
      int64_t j = i - XN4;
      const float* src = (j < WN4) ? wq : ((j < 2 * WN4) ? wk : wv);
      int64_t jj = j & (WN4 - 1);
      f32x4 v = ((const f32x4*)src)[jj];
      bf16x4 o;
#pragma unroll
      for (int q = 0; q < 4; ++q) o[q] = f2b(v[q]);
      ((bf16x4*)Wqkv)[j] = o;
    } else if (i < XN4 + 4 * WN4) {
      int64_t j = i - XN4 - 3 * WN4;
      f32x4 v = ((const f32x4*)wo)[j];
      bf16x4 o;
#pragma unroll
      for (int q = 0; q < 4; ++q) o[q] = f2b(v[q]);
      ((bf16x4*)Wob)[j] = o;
    } else {
      int64_t j = i - XN4 - 4 * WN4;   // 0..511
      int pos = (int)(j >> 5), f = (int)(j & 31);
      float a = rope[pos * 32 + f];
      costab[j] = cosf(a);
      sintab[j] = sinf(a);
    }
  }
}

// ---------- bf16 GEMM, C = A(MxK) * B^T (B stored [N][K]) ----------
// m97 structure: 128x128 tile, BK=32, 4 waves (2x2), 4x4 16x16x32 frags/wave.
__device__ __forceinline__ void storeC(short* C, size_t idx, float v) { C[idx] = f2b(v); }
__device__ __forceinline__ void storeC(float* C, size_t idx, float v) { C[idx] = v; }

template <typename OutT>
__global__ __launch_bounds__(256)
void gemm_bt(const short* __restrict__ A, const short* __restrict__ Bw,
             OutT* __restrict__ C, int M, int N, int K)
{
  __shared__ short As[128 * 32];
  __shared__ short Bs[128 * 32];
  const int t = threadIdx.x;
  const int lane = t & 63;
  const int wid = t >> 6;
  const int wm = wid >> 1, wn = wid & 1;
  const int ntn = N >> 7;
  const int m0 = (blockIdx.x / ntn) << 7;
  const int n0 = (blockIdx.x % ntn) << 7;

  const int lr = lane & 15;
  const int lk = (lane >> 4) << 3;

  f32x4 acc[4][4];
#pragma unroll
  for (int m = 0; m < 4; ++m)
#pragma unroll
    for (int n = 0; n < 4; ++n) acc[m][n] = (f32x4){0.f, 0.f, 0.f, 0.f};

  const int c0 = wid * 2, c1 = wid * 2 + 1;
  const int e0 = (c0 * 64 + lane) * 8, e1 = (c1 * 64 + lane) * 8;
  const int r0 = e0 >> 5, cc0 = e0 & 31;
  const int r1 = e1 >> 5, cc1 = e1 & 31;

  for (int k0 = 0; k0 < K; k0 += 32) {
    gload_lds16(A + (size_t)(m0 + r0) * K + k0 + cc0, (char*)As + c0 * 1024);
    gload_lds16(A + (size_t)(m0 + r1) * K + k0 + cc1, (char*)As + c1 * 1024);
    gload_lds16(Bw + (size_t)(n0 + r0) * K + k0 + cc0, (char*)Bs + c0 * 1024);
    gload_lds16(Bw + (size_t)(n0 + r1) * K + k0 + cc1, (char*)Bs + c1 * 1024);
    asm volatile("s_waitcnt vmcnt(0)" ::: "memory");
    __syncthreads();

    bf16x8 af[4], bfr[4];
#pragma unroll
    for (int m = 0; m < 4; ++m)
      af[m] = *(const bf16x8*)&As[(wm * 64 + m * 16 + lr) * 32 + lk];
#pragma unroll
    for (int n = 0; n < 4; ++n)
      bfr[n] = *(const bf16x8*)&Bs[(wn * 64 + n * 16 + lr) * 32 + lk];
#pragma unroll
    for (int m = 0; m < 4; ++m)
#pragma unroll
      for (int n = 0; n < 4; ++n)
        acc[m][n] = __builtin_amdgcn_mfma_f32_16x16x32_bf16(af[m], bfr[n], acc[m][n], 0, 0, 0);
    __syncthreads();
  }

  const int orow = m0 + wm * 64 + ((lane >> 4) << 2);
  const int ocol = n0 + wn * 64 + lr;
#pragma unroll
  for (int m = 0; m < 4; ++m)
#pragma unroll
    for (int n = 0; n < 4; ++n) {
      f32x4 v = acc[m][n];
#pragma unroll
      for (int i = 0; i < 4; ++i)
        storeC(C, (size_t)(orow + m * 16 + i) * N + (ocol + n * 16), v[i]);
    }
}

// ---------- windowed attention: one wave per (window, head) ----------
__global__ __launch_bounds__(256)
void attn_win(const short* __restrict__ QKV,   // [16384][3072] = q|k|v
              const float* __restrict__ costab, const float* __restrict__ sintab,
              short* __restrict__ Attn)        // [16384][1024]
{
  __shared__ float Plds[4][16][17];
  __shared__ short Vlds[4][16][64];
  const int t = threadIdx.x, lane = t & 63, wid = t >> 6;
  const int pair = blockIdx.x * 4 + wid;       // window*16 + head
  const int win = pair >> 4, h = pair & 15;
  const int lr = lane & 15;                    // token row within window
  const int lk = (lane >> 4) << 3;             // dim sub-offset 0,8,16,24

  const size_t rowb = (size_t)(win * 16 + lr) * 3072;
  const short* qp = QKV + rowb + h * 64;
  const short* kp = qp + 1024;

  bf16x8 q0 = *(const bf16x8*)(qp + lk);
  bf16x8 q1 = *(const bf16x8*)(qp + 32 + lk);
  bf16x8 k0 = *(const bf16x8*)(kp + lk);
  bf16x8 k1 = *(const bf16x8*)(kp + 32 + lk);

  // stage V tile [16][64] into LDS (2 x 16B per lane)
#pragma unroll
  for (int j = 0; j < 2; ++j) {
    int e = (j * 64 + lane) * 8;
    int vr = e >> 6, vc = e & 63;
    *(bf16x8*)&Vlds[wid][vr][vc] =
        *(const bf16x8*)(QKV + (size_t)(win * 16 + vr) * 3072 + 2048 + h * 64 + vc);
  }

  // in-register RoPE: pair (d, d+32) lives in (q0[j], q1[j]) of the same lane
  bf16x8 a0, a1, b0, b1;
#pragma unroll
  for (int j = 0; j < 8; ++j) {
    int f = lk + j;
    float c = costab[lr * 32 + f], s = sintab[lr * 32 + f];
    float x1 = b2f(q0[j]), x2 = b2f(q1[j]);
    a0[j] = f2b(x1 * c - x2 * s);
    a1[j] = f2b(x1 * s + x2 * c);
    float y1 = b2f(k0[j]), y2 = b2f(k1[j]);
    b0[j] = f2b(y1 * c - y2 * s);
    b1[j] = f2b(y1 * s + y2 * c);
  }

  // scores = q . k^T  (16x16, K=64 via two K=32 MFMAs)
  f32x4 sc = (f32x4){0.f, 0.f, 0.f, 0.f};
  sc = __builtin_amdgcn_mfma_f32_16x16x32_bf16(a0, b0, sc, 0, 0, 0);
  sc = __builtin_amdgcn_mfma_f32_16x16x32_bf16(a1, b1, sc, 0, 0, 0);

  // softmax over cols (col = lane&15; reduce across the 16-lane group)
  float p[4];
#pragma unroll
  for (int i = 0; i < 4; ++i) {
    float v = sc[i] * 0.125f;   // 1/sqrt(64)
    float m = v;
#pragma unroll
    for (int msk = 1; msk < 16; msk <<= 1) m = fmaxf(m, __shfl_xor(m, msk));
    float e = __expf(v - m);
    float s = e;
#pragma unroll
    for (int msk = 1; msk < 16; msk <<= 1) s += __shfl_xor(s, msk);
    p[i] = e / s;
  }
#pragma unroll
  for (int i = 0; i < 4; ++i)
    Plds[wid][((lane >> 4) << 2) + i][lr] = p[i];

  __syncthreads();

  // PV: lane owns (row r = lane&15, d-block = lane>>4), 16 outputs
  const int r = lr, dblk = lane >> 4;
  float a[16];
#pragma unroll
  for (int j = 0; j < 16; ++j) a[j] = 0.f;
#pragma unroll
  for (int k = 0; k < 16; ++k) {
    float pk = Plds[wid][r][k];
    bf16x8 v0 = *(const bf16x8*)&Vlds[wid][k][dblk * 16];
    bf16x8 v1 = *(const bf16x8*)&Vlds[wid][k][dblk * 16 + 8];
#pragma unroll
    for (int j = 0; j < 8; ++j) {
      a[j]     += pk * b2f(v0[j]);
      a[8 + j] += pk * b2f(v1[j]);
    }
  }
  bf16x8 o0, o1;
#pragma unroll
  for (int j = 0; j < 8; ++j) { o0[j] = f2b(a[j]); o1[j] = f2b(a[8 + j]); }
  short* op = Attn + (size_t)(win * 16 + r) * 1024 + h * 64 + dblk * 16;
  *(bf16x8*)op = o0;
  *(bf16x8*)(op + 8) = o1;
}

// ---------- launch ----------
extern "C" void kernel_launch(void* const* d_in, const int* in_sizes, int n_in,
                              void* d_out, int out_size, void* d_ws, size_t ws_size,
                              hipStream_t stream)
{
  const float* x  = (const float*)d_in[0];
  const float* rf = (const float*)d_in[1];
  const float* wq = (const float*)d_in[2];
  const float* wk = (const float*)d_in[3];
  const float* wv = (const float*)d_in[4];
  const float* wo = (const float*)d_in[5];
  float* out = (float*)d_out;

  char* w = (char*)d_ws;
  short* Xb     = (short*)(w);                          // 33,554,432 B
  short* Wqkv   = (short*)(w + 33554432);               //  6,291,456 B
  short* Wob    = (short*)(w + 39845888);               //  2,097,152 B
  short* QKV    = (short*)(w + 41943040);               // 100,663,296 B
  short* Attn   = (short*)(w + 142606336);              // 33,554,432 B
  float* costab = (float*)(w + 176160768);              // 2,048 B
  float* sintab = (float*)(w + 176162816);              // 2,048 B  (total ~176.2 MB)

  prep<<<2048, 256, 0, stream>>>(x, rf, wq, wk, wv, wo, Xb, Wqkv, Wob, costab, sintab);
  gemm_bt<short><<<3072, 256, 0, stream>>>(Xb, Wqkv, QKV, 16384, 3072, 1024);
  attn_win<<<4096, 256, 0, stream>>>(QKV, costab, sintab, Attn);
  gemm_bt<float><<<1024, 256, 0, stream>>>(Attn, Wob, out, 16384, 1024, 1024);
}

// Round 2
// 353.828 us; speedup vs baseline: 1.0358x; 1.0358x over previous
//
#include <hip/hip_runtime.h>
#include <hip/hip_bf16.h>
#include <stdint.h>

// ---------- types ----------
typedef short bf16x8 __attribute__((ext_vector_type(8)));
typedef short bf16x4 __attribute__((ext_vector_type(4)));
typedef float f32x4  __attribute__((ext_vector_type(4)));

__device__ __forceinline__ float b2f(short s) {
  union { float f; uint32_t u; } x;
  x.u = ((uint32_t)(uint16_t)s) << 16;
  return x.f;
}
__device__ __forceinline__ short f2b(float f) {
  union { float f; uint32_t u; } x;
  x.f = f;
  uint32_t r = x.u + 0x7fff + ((x.u >> 16) & 1);  // RNE
  return (short)(r >> 16);
}

__device__ __forceinline__ void gload_lds16(const void* g, void* l) {
  __builtin_amdgcn_global_load_lds(
      (const __attribute__((address_space(1))) void*)g,
      (__attribute__((address_space(3))) void*)l, 16, 0, 0);
}

// ---------- prep: f32 -> bf16 conversions + rope tables ----------
__global__ __launch_bounds__(256)
void prep(const float* __restrict__ x, const float* __restrict__ rope,
          const float* __restrict__ wq, const float* __restrict__ wk,
          const float* __restrict__ wv, const float* __restrict__ wo,
          short* __restrict__ Xb, short* __restrict__ Wqkv, short* __restrict__ Wob,
          float* __restrict__ costab, float* __restrict__ sintab)
{
  const int64_t XN4 = 16777216 / 4;   // x float4 count
  const int64_t WN4 = 1048576 / 4;    // one weight matrix float4 count
  const int64_t total = XN4 + 4 * WN4 + 512;
  for (int64_t i = (int64_t)blockIdx.x * blockDim.x + threadIdx.x; i < total;
       i += (int64_t)gridDim.x * blockDim.x) {
    if (i < XN4) {
      f32x4 v = ((const f32x4*)x)[i];
      bf16x4 o;
#pragma unroll
      for (int j = 0; j < 4; ++j) o[j] = f2b(v[j]);
      ((bf16x4*)Xb)[i] = o;
    } else if (i < XN4 + 3 * WN4) {
      int64_t j = i - XN4;
      const float* src = (j < WN4) ? wq : ((j < 2 * WN4) ? wk : wv);
      int64_t jj = j & (WN4 - 1);
      f32x4 v = ((const f32x4*)src)[jj];
      bf16x4 o;
#pragma unroll
      for (int q = 0; q < 4; ++q) o[q] = f2b(v[q]);
      ((bf16x4*)Wqkv)[j] = o;
    } else if (i < XN4 + 4 * WN4) {
      int64_t j = i - XN4 - 3 * WN4;
      f32x4 v = ((const f32x4*)wo)[j];
      bf16x4 o;
#pragma unroll
      for (int q = 0; q < 4; ++q) o[q] = f2b(v[q]);
      ((bf16x4*)Wob)[j] = o;
    } else {
      int64_t j = i - XN4 - 4 * WN4;   // 0..511
      int pos = (int)(j >> 5), f = (int)(j & 31);
      float a = rope[pos * 32 + f];
      costab[j] = cosf(a);
      sintab[j] = sinf(a);
    }
  }
}

// ---------- deep-pipelined bf16 GEMM, C = A(MxK) * B^T (B stored [N][K]) ----------
// BM=128, BN=256, BK=64. 8 waves (2Mx4N), 64x64 out/wave.
// 3 LDS buffers (48 KB each = A 16 KB + B 32 KB), prefetch distance 2,
// counted vmcnt(6), one raw s_barrier per K-tile, T2 XOR swizzle, T5 setprio.
__device__ __forceinline__ void store4(short* C, size_t idx, f32x4 v) {
  bf16x4 o;
#pragma unroll
  for (int j = 0; j < 4; ++j) o[j] = f2b(v[j]);
  *(bf16x4*)(C + idx) = o;
}
__device__ __forceinline__ void store4(float* C, size_t idx, f32x4 v) {
  *(f32x4*)(C + idx) = v;
}

template <typename OutT>
__global__ __launch_bounds__(512, 2)
void gemm_bt2(const short* __restrict__ A, const short* __restrict__ Bw,
              OutT* __restrict__ C, int M, int N, int K, int nmt)
{
  __shared__ __align__(16) char lds[147456];   // 3 x (16384 A + 32768 B)
  const int t = threadIdx.x;
  const int lane = t & 63;
  const int wid = t >> 6;       // 0..7
  const int wm = wid >> 2;      // 0..1
  const int wn = wid & 3;       // 0..3

  // XCD-bijective swizzle (nwg % 8 == 0 for our grids), mt-fastest for L2 B-reuse
  int nwg = gridDim.x;
  int bid = blockIdx.x;
  int swz = ((nwg & 7) == 0) ? ((bid & 7) * (nwg >> 3) + (bid >> 3)) : bid;
  const int mt = swz % nmt;
  const int nt = swz / nmt;
  const int m0 = mt << 7;       // BM=128
  const int n0 = nt << 8;       // BN=256

  const int T = K >> 6;         // BK=64 elements

  const int r_a  = lane >> 3;   // row-within-8 for staging
  const int csrc = lane & 7;    // 16B slot for staging (pre-swizzled source)

  // ---- staging: linear LDS dest, inverse-swizzled global source ----
  auto stageA = [&](int kt, int buf) {
    char* base = lds + buf * 49152;
#pragma unroll
    for (int j = 0; j < 2; ++j) {
      int chunk = j * 8 + wid;            // 16 x 1 KB chunks
      int r = chunk * 8 + r_a;            // 0..127
      int sl = csrc ^ (r & 7);
      gload_lds16(A + (size_t)(m0 + r) * K + (kt << 6) + (sl << 3),
                  base + chunk * 1024);
    }
  };
  auto stageB = [&](int kt, int buf) {
    char* base = lds + buf * 49152 + 16384;
#pragma unroll
    for (int j = 0; j < 4; ++j) {
      int chunk = j * 8 + wid;            // 32 x 1 KB chunks
      int r = chunk * 8 + r_a;            // 0..255
      int sl = csrc ^ (r & 7);
      gload_lds16(Bw + (size_t)(n0 + r) * K + (kt << 6) + (sl << 3),
                  base + chunk * 1024);
    }
  };

  f32x4 acc[4][4];
#pragma unroll
  for (int m = 0; m < 4; ++m)
#pragma unroll
    for (int n = 0; n < 4; ++n) acc[m][n] = (f32x4){0.f, 0.f, 0.f, 0.f};

  const int lr = lane & 15;
  const int ls = lane >> 4;     // 0..3
  const int axor = lr & 7;      // swizzle term (row & 7)

  // prologue: stage tiles 0 and 1
  stageA(0, 0); stageB(0, 0);
  if (T > 1) { stageA(1, 1); stageB(1, 1); }

  for (int kt = 0; kt < T; ++kt) {
    if (kt + 1 < T) asm volatile("s_waitcnt vmcnt(6)" ::: "memory");
    else            asm volatile("s_waitcnt vmcnt(0)" ::: "memory");
    __builtin_amdgcn_s_barrier();
    __builtin_amdgcn_sched_barrier(0);

    const int buf = kt % 3;
    if (kt + 2 < T) { const int nb = (kt + 2) % 3; stageA(kt + 2, nb); stageB(kt + 2, nb); }

    const char* ab = lds + buf * 49152;
    const char* bb = ab + 16384;
    bf16x8 af[2][4], bfr[2][4];
#pragma unroll
    for (int kk = 0; kk < 2; ++kk) {
      const int u = (((kk << 2) + ls) ^ axor) << 4;
#pragma unroll
      for (int m4 = 0; m4 < 4; ++m4)
        af[kk][m4] = *(const bf16x8*)(ab + (wm * 64 + m4 * 16 + lr) * 128 + u);
#pragma unroll
      for (int n4 = 0; n4 < 4; ++n4)
        bfr[kk][n4] = *(const bf16x8*)(bb + (wn * 64 + n4 * 16 + lr) * 128 + u);
    }

    __builtin_amdgcn_s_setprio(1);
#pragma unroll
    for (int kk = 0; kk < 2; ++kk)
#pragma unroll
      for (int m4 = 0; m4 < 4; ++m4)
#pragma unroll
        for (int n4 = 0; n4 < 4; ++n4)
          // swapped operands: D[row=lane&15 (M)][col=(lane>>4)*4+i (N)]
          acc[m4][n4] = __builtin_amdgcn_mfma_f32_16x16x32_bf16(
              bfr[kk][n4], af[kk][m4], acc[m4][n4], 0, 0, 0);
    __builtin_amdgcn_s_setprio(0);
  }

  // epilogue: per-lane 4 consecutive N-cols -> vectorized stores
  const int orow = m0 + wm * 64 + lr;
  const int ocol = n0 + wn * 64 + ls * 4;
#pragma unroll
  for (int m4 = 0; m4 < 4; ++m4)
#pragma unroll
    for (int n4 = 0; n4 < 4; ++n4)
      store4(C, (size_t)(orow + m4 * 16) * N + (ocol + n4 * 16), acc[m4][n4]);
}

// ---------- windowed attention: one wave per (window, head) ----------
__global__ __launch_bounds__(256)
void attn_win(const short* __restrict__ QKV,   // [16384][3072] = q|k|v
              const float* __restrict__ costab, const float* __restrict__ sintab,
              short* __restrict__ Attn)        // [16384][1024]
{
  __shared__ float Plds[4][16][17];
  __shared__ short Vlds[4][16][64];
  const int t = threadIdx.x, lane = t & 63, wid = t >> 6;
  const int pair = blockIdx.x * 4 + wid;       // window*16 + head
  const int win = pair >> 4, h = pair & 15;
  const int lr = lane & 15;                    // token row within window
  const int lk = (lane >> 4) << 3;             // dim sub-offset 0,8,16,24

  const size_t rowb = (size_t)(win * 16 + lr) * 3072;
  const short* qp = QKV + rowb + h * 64;
  const short* kp = qp + 1024;

  bf16x8 q0 = *(const bf16x8*)(qp + lk);
  bf16x8 q1 = *(const bf16x8*)(qp + 32 + lk);
  bf16x8 k0 = *(const bf16x8*)(kp + lk);
  bf16x8 k1 = *(const bf16x8*)(kp + 32 + lk);

  // stage V tile [16][64] into LDS (2 x 16B per lane)
#pragma unroll
  for (int j = 0; j < 2; ++j) {
    int e = (j * 64 + lane) * 8;
    int vr = e >> 6, vc = e & 63;
    *(bf16x8*)&Vlds[wid][vr][vc] =
        *(const bf16x8*)(QKV + (size_t)(win * 16 + vr) * 3072 + 2048 + h * 64 + vc);
  }

  // in-register RoPE: pair (d, d+32) lives in (q0[j], q1[j]) of the same lane
  bf16x8 a0, a1, b0, b1;
#pragma unroll
  for (int j = 0; j < 8; ++j) {
    int f = lk + j;
    float c = costab[lr * 32 + f], s = sintab[lr * 32 + f];
    float x1 = b2f(q0[j]), x2 = b2f(q1[j]);
    a0[j] = f2b(x1 * c - x2 * s);
    a1[j] = f2b(x1 * s + x2 * c);
    float y1 = b2f(k0[j]), y2 = b2f(k1[j]);
    b0[j] = f2b(y1 * c - y2 * s);
    b1[j] = f2b(y1 * s + y2 * c);
  }

  // scores = q . k^T  (16x16, K=64 via two K=32 MFMAs)
  f32x4 sc = (f32x4){0.f, 0.f, 0.f, 0.f};
  sc = __builtin_amdgcn_mfma_f32_16x16x32_bf16(a0, b0, sc, 0, 0, 0);
  sc = __builtin_amdgcn_mfma_f32_16x16x32_bf16(a1, b1, sc, 0, 0, 0);

  // softmax over cols (col = lane&15; reduce across the 16-lane group)
  float p[4];
#pragma unroll
  for (int i = 0; i < 4; ++i) {
    float v = sc[i] * 0.125f;   // 1/sqrt(64)
    float m = v;
#pragma unroll
    for (int msk = 1; msk < 16; msk <<= 1) m = fmaxf(m, __shfl_xor(m, msk));
    float e = __expf(v - m);
    float s = e;
#pragma unroll
    for (int msk = 1; msk < 16; msk <<= 1) s += __shfl_xor(s, msk);
    p[i] = e / s;
  }
#pragma unroll
  for (int i = 0; i < 4; ++i)
    Plds[wid][((lane >> 4) << 2) + i][lr] = p[i];

  __syncthreads();

  // PV: lane owns (row r = lane&15, d-block = lane>>4), 16 outputs
  const int r = lr, dblk = lane >> 4;
  float a[16];
#pragma unroll
  for (int j = 0; j < 16; ++j) a[j] = 0.f;
#pragma unroll
  for (int k = 0; k < 16; ++k) {
    float pk = Plds[wid][r][k];
    bf16x8 v0 = *(const bf16x8*)&Vlds[wid][k][dblk * 16];
    bf16x8 v1 = *(const bf16x8*)&Vlds[wid][k][dblk * 16 + 8];
#pragma unroll
    for (int j = 0; j < 8; ++j) {
      a[j]     += pk * b2f(v0[j]);
      a[8 + j] += pk * b2f(v1[j]);
    }
  }
  bf16x8 o0, o1;
#pragma unroll
  for (int j = 0; j < 8; ++j) { o0[j] = f2b(a[j]); o1[j] = f2b(a[8 + j]); }
  short* op = Attn + (size_t)(win * 16 + r) * 1024 + h * 64 + dblk * 16;
  *(bf16x8*)op = o0;
  *(bf16x8*)(op + 8) = o1;
}

// ---------- launch ----------
extern "C" void kernel_launch(void* const* d_in, const int* in_sizes, int n_in,
                              void* d_out, int out_size, void* d_ws, size_t ws_size,
                              hipStream_t stream)
{
  const float* x  = (const float*)d_in[0];
  const float* rf = (const float*)d_in[1];
  const float* wq = (const float*)d_in[2];
  const float* wk = (const float*)d_in[3];
  const float* wv = (const float*)d_in[4];
  const float* wo = (const float*)d_in[5];
  float* out = (float*)d_out;

  char* w = (char*)d_ws;
  short* Xb     = (short*)(w);                          // 33,554,432 B
  short* Wqkv   = (short*)(w + 33554432);               //  6,291,456 B
  short* Wob    = (short*)(w + 39845888);               //  2,097,152 B
  short* QKV    = (short*)(w + 41943040);               // 100,663,296 B
  short* Attn   = (short*)(w + 142606336);              // 33,554,432 B
  float* costab = (float*)(w + 176160768);              // 2,048 B
  float* sintab = (float*)(w + 176162816);              // 2,048 B

  prep<<<2048, 256, 0, stream>>>(x, rf, wq, wk, wv, wo, Xb, Wqkv, Wob, costab, sintab);
  // QKV: M=16384, N=3072, K=1024 -> grid (16384/128)*(3072/256) = 128*12 = 1536
  gemm_bt2<short><<<1536, 512, 0, stream>>>(Xb, Wqkv, QKV, 16384, 3072, 1024, 128);
  attn_win<<<4096, 256, 0, stream>>>(QKV, costab, sintab, Attn);
  // WO: M=16384, N=1024, K=1024 -> grid 128*4 = 512
  gemm_bt2<float><<<512, 512, 0, stream>>>(Attn, Wob, out, 16384, 1024, 1024, 128);
}

// Round 5
// 332.217 us; speedup vs baseline: 1.1032x; 1.0651x over previous
//
#include <hip/hip_runtime.h>
#include <hip/hip_bf16.h>
#include <stdint.h>

// ---------- types ----------
typedef short bf16x8 __attribute__((ext_vector_type(8)));
typedef short bf16x4 __attribute__((ext_vector_type(4)));
typedef float f32x4  __attribute__((ext_vector_type(4)));

__device__ __forceinline__ float b2f(short s) {
  union { float f; uint32_t u; } x;
  x.u = ((uint32_t)(uint16_t)s) << 16;
  return x.f;
}
__device__ __forceinline__ short f2b(float f) {
  union { float f; uint32_t u; } x;
  x.f = f;
  uint32_t r = x.u + 0x7fff + ((x.u >> 16) & 1);  // RNE
  return (short)(r >> 16);
}

__device__ __forceinline__ void gload_lds16(const void* g, void* l) {
  __builtin_amdgcn_global_load_lds(
      (const __attribute__((address_space(1))) void*)g,
      (__attribute__((address_space(3))) void*)l, 16, 0, 0);
}

// ---------- prep: f32 -> bf16 conversions + rope tables ----------
__global__ __launch_bounds__(256)
void prep(const float* __restrict__ x, const float* __restrict__ rope,
          const float* __restrict__ wq, const float* __restrict__ wk,
          const float* __restrict__ wv, const float* __restrict__ wo,
          short* __restrict__ Xb, short* __restrict__ Wqkv, short* __restrict__ Wob,
          float* __restrict__ costab, float* __restrict__ sintab)
{
  const int64_t XN4 = 16777216 / 4;   // x float4 count
  const int64_t WN4 = 1048576 / 4;    // one weight matrix float4 count
  const int64_t total = XN4 + 4 * WN4 + 512;
  for (int64_t i = (int64_t)blockIdx.x * blockDim.x + threadIdx.x; i < total;
       i += (int64_t)gridDim.x * blockDim.x) {
    if (i < XN4) {
      f32x4 v = ((const f32x4*)x)[i];
      bf16x4 o;
#pragma unroll
      for (int j = 0; j < 4; ++j) o[j] = f2b(v[j]);
      ((bf16x4*)Xb)[i] = o;
    } else if (i < XN4 + 3 * WN4) {
      int64_t j = i - XN4;
      const float* src = (j < WN4) ? wq : ((j < 2 * WN4) ? wk : wv);
      int64_t jj = j & (WN4 - 1);
      f32x4 v = ((const f32x4*)src)[jj];
      bf16x4 o;
#pragma unroll
      for (int q = 0; q < 4; ++q) o[q] = f2b(v[q]);
      ((bf16x4*)Wqkv)[j] = o;
    } else if (i < XN4 + 4 * WN4) {
      int64_t j = i - XN4 - 3 * WN4;
      f32x4 v = ((const f32x4*)wo)[j];
      bf16x4 o;
#pragma unroll
      for (int q = 0; q < 4; ++q) o[q] = f2b(v[q]);
      ((bf16x4*)Wob)[j] = o;
    } else {
      int64_t j = i - XN4 - 4 * WN4;   // 0..511
      int pos = (int)(j >> 5), f = (int)(j & 31);
      float a = rope[pos * 32 + f];
      costab[j] = cosf(a);
      sintab[j] = sinf(a);
    }
  }
}

// ---------- 8-phase deep-pipelined bf16 GEMM, C = A(MxK) * B^T ----------
// BM=BN=256, BK=64, 512 threads, 8 waves (2Mx4N), 128x64 out/wave.
// LDS 128 KiB = 2 buf x (A 32K + B 32K). 4 phases/K-tile, each: 16 MFMA on one
// C-quadrant. 4 stage units/tile (A-U0,B-U0,B-U1,A-U1), one staged per phase,
// counted vmcnt(4), XOR-swizzled zero-conflict layout (measured r2: 0 conflicts).
__device__ __forceinline__ void store4(short* C, size_t idx, f32x4 v) {
  bf16x4 o;
#pragma unroll
  for (int j = 0; j < 4; ++j) o[j] = f2b(v[j]);
  *(bf16x4*)(C + idx) = o;
}
__device__ __forceinline__ void store4(float* C, size_t idx, f32x4 v) {
  *(f32x4*)(C + idx) = v;
}

template <typename OutT>
__global__ __launch_bounds__(512, 2)
void gemm_bt3(const short* __restrict__ A, const short* __restrict__ Bw,
              OutT* __restrict__ C, int M, int N, int K, int nmt)
{
  __shared__ __align__(16) char lds[131072];  // [buf][A 32K | B 32K]
  const int t = threadIdx.x, lane = t & 63, wid = t >> 6;
  const int wm = wid >> 2, wn = wid & 3;      // 2M x 4N wave grid
  const int lr = lane & 15, ls = lane >> 4;

  const int nwg = gridDim.x, bid = blockIdx.x;
  const int swz = (bid & 7) * (nwg >> 3) + (bid >> 3);   // bijective (nwg%8==0)
  const int mt = swz % nmt, nt = swz / nmt;
  const int m0 = mt << 8, n0 = nt << 8;
  const int T = K >> 6;

  // staging lane geometry: 1KB chunk = 8 rows x 128B; source granule pre-swizzled
  const int srow8 = lane >> 3;                   // row within chunk
  const int sgr   = (lane & 7) ^ srow8;          // swizzled 16B granule

  // A-U(rh): rows {rh*64..rh*64+63} u {128+rh*64..}; 16 chunks, wave does wid, wid+8
  auto stageA = [&](int kt, int rh) {
    char* base = lds + (kt & 1) * 65536;
#pragma unroll
    for (int j = 0; j < 2; ++j) {
      int c  = j * 8 + wid;
      int rb = (c >> 3) * 128 + rh * 64 + (c & 7) * 8;
      gload_lds16(A + (size_t)(m0 + rb + srow8) * K + (kt << 6) + (sgr << 3),
                  base + rb * 128);
    }
  };
  // B-U(ch): rows {q*64+ch*32 .. +31 : q=0..3}; 16 chunks
  auto stageB = [&](int kt, int ch) {
    char* base = lds + (kt & 1) * 65536 + 32768;
#pragma unroll
    for (int j = 0; j < 2; ++j) {
      int c  = j * 8 + wid;
      int rb = (c >> 2) * 64 + ch * 32 + (c & 3) * 8;
      gload_lds16(Bw + (size_t)(n0 + rb + srow8) * K + (kt << 6) + (sgr << 3),
                  base + rb * 128);
    }
  };

  f32x4 acc[8][4];
#pragma unroll
  for (int m = 0; m < 8; ++m)
#pragma unroll
    for (int n = 0; n < 4; ++n) acc[m][n] = (f32x4){0.f, 0.f, 0.f, 0.f};

  bf16x8 a[2][4], b[2][2];
  auto ldA = [&](int kt, int rh) {
    const char* base = lds + (kt & 1) * 65536;
#pragma unroll
    for (int kk = 0; kk < 2; ++kk)
#pragma unroll
      for (int i = 0; i < 4; ++i) {
        int row = wm * 128 + (rh * 4 + i) * 16 + lr;
        int u = ((kk << 2) + ls) ^ (lr & 7);
        a[kk][i] = *(const bf16x8*)(base + row * 128 + u * 16);
      }
  };
  auto ldB = [&](int kt, int ch) {
    const char* base = lds + (kt & 1) * 65536 + 32768;
#pragma unroll
    for (int kk = 0; kk < 2; ++kk)
#pragma unroll
      for (int j = 0; j < 2; ++j) {
        int row = wn * 64 + (ch * 2 + j) * 16 + lr;
        int u = ((kk << 2) + ls) ^ (lr & 7);
        b[kk][j] = *(const bf16x8*)(base + row * 128 + u * 16);
      }
  };
  auto mfma16 = [&](int rh, int ch) {
    __builtin_amdgcn_s_setprio(1);
#pragma unroll
    for (int kk = 0; kk < 2; ++kk)
#pragma unroll
      for (int i = 0; i < 4; ++i)
#pragma unroll
        for (int j = 0; j < 2; ++j)
          acc[rh * 4 + i][ch * 2 + j] = __builtin_amdgcn_mfma_f32_16x16x32_bf16(
              b[kk][j], a[kk][i], acc[rh * 4 + i][ch * 2 + j], 0, 0, 0);
    __builtin_amdgcn_s_setprio(0);
  };

  // prologue: stage all 4 units of tile 0 (issue order = steady-state order)
  stageA(0, 0); stageB(0, 0); stageB(0, 1); stageA(0, 1);
  asm volatile("s_waitcnt vmcnt(4)" ::: "memory");   // A-U0(0), B-U0(0) landed
  __builtin_amdgcn_s_barrier();

  for (int kt = 0; kt < T; ++kt) {
    const bool pf = (kt + 1 < T);
    // ---- phase 0: quadrant (rh0, ch0) ---- reads A-U0(kt), B-U0(kt)
    ldA(kt, 0); ldB(kt, 0);
    if (pf) { stageA(kt + 1, 0); asm volatile("s_waitcnt vmcnt(4)" ::: "memory"); }
    else    {                    asm volatile("s_waitcnt vmcnt(2)" ::: "memory"); }
    asm volatile("s_waitcnt lgkmcnt(8)" ::: "memory");
    __builtin_amdgcn_s_barrier();
    asm volatile("s_waitcnt lgkmcnt(0)" ::: "memory");
    __builtin_amdgcn_sched_barrier(0);
    mfma16(0, 0);
    __builtin_amdgcn_s_barrier();
    // ---- phase 1: (rh0, ch1) ---- keeps A, reads B-U1(kt)
    ldB(kt, 1);
    if (pf) { stageB(kt + 1, 0); asm volatile("s_waitcnt vmcnt(4)" ::: "memory"); }
    else    {                    asm volatile("s_waitcnt vmcnt(0)" ::: "memory"); }
    __builtin_amdgcn_s_barrier();
    asm volatile("s_waitcnt lgkmcnt(0)" ::: "memory");
    __builtin_amdgcn_sched_barrier(0);
    mfma16(0, 1);
    __builtin_amdgcn_s_barrier();
    // ---- phase 2: (rh1, ch1) ---- keeps B, reads A-U1(kt)
    ldA(kt, 1);
    if (pf) stageB(kt + 1, 1);
    __builtin_amdgcn_s_barrier();
    asm volatile("s_waitcnt lgkmcnt(0)" ::: "memory");
    __builtin_amdgcn_sched_barrier(0);
    mfma16(1, 1);
    __builtin_amdgcn_s_barrier();
    // ---- phase 3: (rh1, ch0) ---- keeps A, re-reads B-U0(kt)
    ldB(kt, 0);
    if (pf) { stageA(kt + 1, 1); asm volatile("s_waitcnt vmcnt(4)" ::: "memory"); }
    __builtin_amdgcn_s_barrier();
    asm volatile("s_waitcnt lgkmcnt(0)" ::: "memory");
    __builtin_amdgcn_sched_barrier(0);
    mfma16(1, 0);
    __builtin_amdgcn_s_barrier();
  }

  // epilogue: lane holds rows (lr + m4*16), 4 consecutive N-cols per acc
  const int orow = m0 + wm * 128 + lr;
  const int ocol = n0 + wn * 64 + ls * 4;
#pragma unroll
  for (int m4 = 0; m4 < 8; ++m4)
#pragma unroll
    for (int n4 = 0; n4 < 4; ++n4)
      store4(C, (size_t)(orow + m4 * 16) * N + (ocol + n4 * 16), acc[m4][n4]);
}

// ---------- windowed attention: one wave per (window, head) ----------
__global__ __launch_bounds__(256)
void attn_win(const short* __restrict__ QKV,   // [16384][3072] = q|k|v
              const float* __restrict__ costab, const float* __restrict__ sintab,
              short* __restrict__ Attn)        // [16384][1024]
{
  __shared__ float Plds[4][16][17];
  __shared__ short Vlds[4][16][64];
  const int t = threadIdx.x, lane = t & 63, wid = t >> 6;
  const int pair = blockIdx.x * 4 + wid;       // window*16 + head
  const int win = pair >> 4, h = pair & 15;
  const int lr = lane & 15;                    // token row within window
  const int lk = (lane >> 4) << 3;             // dim sub-offset 0,8,16,24

  const size_t rowb = (size_t)(win * 16 + lr) * 3072;
  const short* qp = QKV + rowb + h * 64;
  const short* kp = qp + 1024;

  bf16x8 q0 = *(const bf16x8*)(qp + lk);
  bf16x8 q1 = *(const bf16x8*)(qp + 32 + lk);
  bf16x8 k0 = *(const bf16x8*)(kp + lk);
  bf16x8 k1 = *(const bf16x8*)(kp + 32 + lk);

  // stage V tile [16][64] into LDS (2 x 16B per lane)
#pragma unroll
  for (int j = 0; j < 2; ++j) {
    int e = (j * 64 + lane) * 8;
    int vr = e >> 6, vc = e & 63;
    *(bf16x8*)&Vlds[wid][vr][vc] =
        *(const bf16x8*)(QKV + (size_t)(win * 16 + vr) * 3072 + 2048 + h * 64 + vc);
  }

  // in-register RoPE: pair (d, d+32) lives in (q0[j], q1[j]) of the same lane
  bf16x8 a0, a1, b0, b1;
#pragma unroll
  for (int j = 0; j < 8; ++j) {
    int f = lk + j;
    float c = costab[lr * 32 + f], s = sintab[lr * 32 + f];
    float x1 = b2f(q0[j]), x2 = b2f(q1[j]);
    a0[j] = f2b(x1 * c - x2 * s);
    a1[j] = f2b(x1 * s + x2 * c);
    float y1 = b2f(k0[j]), y2 = b2f(k1[j]);
    b0[j] = f2b(y1 * c - y2 * s);
    b1[j] = f2b(y1 * s + y2 * c);
  }

  // scores = q . k^T  (16x16, K=64 via two K=32 MFMAs)
  f32x4 sc = (f32x4){0.f, 0.f, 0.f, 0.f};
  sc = __builtin_amdgcn_mfma_f32_16x16x32_bf16(a0, b0, sc, 0, 0, 0);
  sc = __builtin_amdgcn_mfma_f32_16x16x32_bf16(a1, b1, sc, 0, 0, 0);

  // softmax over cols (col = lane&15; reduce across the 16-lane group)
  float p[4];
#pragma unroll
  for (int i = 0; i < 4; ++i) {
    float v = sc[i] * 0.125f;   // 1/sqrt(64)
    float m = v;
#pragma unroll
    for (int msk = 1; msk < 16; msk <<= 1) m = fmaxf(m, __shfl_xor(m, msk));
    float e = __expf(v - m);
    float s = e;
#pragma unroll
    for (int msk = 1; msk < 16; msk <<= 1) s += __shfl_xor(s, msk);
    p[i] = e / s;
  }
#pragma unroll
  for (int i = 0; i < 4; ++i)
    Plds[wid][((lane >> 4) << 2) + i][lr] = p[i];

  __syncthreads();

  // PV: lane owns (row r = lane&15, d-block = lane>>4), 16 outputs
  const int r = lr, dblk = lane >> 4;
  float a[16];
#pragma unroll
  for (int j = 0; j < 16; ++j) a[j] = 0.f;
#pragma unroll
  for (int k = 0; k < 16; ++k) {
    float pk = Plds[wid][r][k];
    bf16x8 v0 = *(const bf16x8*)&Vlds[wid][k][dblk * 16];
    bf16x8 v1 = *(const bf16x8*)&Vlds[wid][k][dblk * 16 + 8];
#pragma unroll
    for (int j = 0; j < 8; ++j) {
      a[j]     += pk * b2f(v0[j]);
      a[8 + j] += pk * b2f(v1[j]);
    }
  }
  bf16x8 o0, o1;
#pragma unroll
  for (int j = 0; j < 8; ++j) { o0[j] = f2b(a[j]); o1[j] = f2b(a[8 + j]); }
  short* op = Attn + (size_t)(win * 16 + r) * 1024 + h * 64 + dblk * 16;
  *(bf16x8*)op = o0;
  *(bf16x8*)(op + 8) = o1;
}

// ---------- launch ----------
extern "C" void kernel_launch(void* const* d_in, const int* in_sizes, int n_in,
                              void* d_out, int out_size, void* d_ws, size_t ws_size,
                              hipStream_t stream)
{
  const float* x  = (const float*)d_in[0];
  const float* rf = (const float*)d_in[1];
  const float* wq = (const float*)d_in[2];
  const float* wk = (const float*)d_in[3];
  const float* wv = (const float*)d_in[4];
  const float* wo = (const float*)d_in[5];
  float* out = (float*)d_out;

  char* w = (char*)d_ws;
  short* Xb     = (short*)(w);                          // 33,554,432 B
  short* Wqkv   = (short*)(w + 33554432);               //  6,291,456 B
  short* Wob    = (short*)(w + 39845888);               //  2,097,152 B
  short* QKV    = (short*)(w + 41943040);               // 100,663,296 B
  short* Attn   = (short*)(w + 142606336);              // 33,554,432 B
  float* costab = (float*)(w + 176160768);              // 2,048 B
  float* sintab = (float*)(w + 176162816);              // 2,048 B

  prep<<<2048, 256, 0, stream>>>(x, rf, wq, wk, wv, wo, Xb, Wqkv, Wob, costab, sintab);
  // QKV: M=16384 (64 mt), N=3072 (12 nt) -> 768 blocks (%8==0)
  gemm_bt3<short><<<768, 512, 0, stream>>>(Xb, Wqkv, QKV, 16384, 3072, 1024, 64);
  attn_win<<<4096, 256, 0, stream>>>(QKV, costab, sintab, Attn);
  // WO: M=16384 (64 mt), N=1024 (4 nt) -> 256 blocks (%8==0)
  gemm_bt3<float><<<256, 512, 0, stream>>>(Attn, Wob, out, 16384, 1024, 1024, 64);
}